// Round 1
// baseline (257.182 us; speedup 1.0000x reference)
//
#include <hip/hip_runtime.h>
#include <stdint.h>

typedef __attribute__((ext_vector_type(8)))  short s16x8;   // 8 x bf16
typedef __attribute__((ext_vector_type(16))) float f32x16;  // 32x32 MFMA acc

union CvtI4 { int4 i; s16x8 s; };

__device__ __forceinline__ unsigned f2bf(float f) {
    union { float f; unsigned u; } v; v.f = f;
    return (v.u + 0x7fffu + ((v.u >> 16) & 1u)) >> 16;     // RNE
}

// ---------------------------------------------------------------------------
// k_prep: grid 1024 = (b, n0-chunk, half). LDS-transpose x tile ->
//   xT[b][n][c] = bf16(x * sqrt(log2e/8)), vbf[b][c][n] = bf16(relu(bn1(w1.x)))
// ---------------------------------------------------------------------------
__global__ __launch_bounds__(256) void k_prep(
    const float* __restrict__ x, const float* __restrict__ w1,
    const float* __restrict__ g1, const float* __restrict__ b1,
    const float* __restrict__ m1, const float* __restrict__ v1,
    unsigned short* __restrict__ xT, unsigned short* __restrict__ vbf)
{
    __shared__ float X[64 * 65];   // [c][n] pad+1
    const int b    = blockIdx.x >> 7;
    const int n0   = ((blockIdx.x >> 1) & 63) << 6;
    const int half = blockIdx.x & 1;
    const int tid  = threadIdx.x;
    const float QS = 0.42466090014400953f;   // sqrt(log2(e)/8)

    {
        const int r = tid >> 6, nn = tid & 63;
        const float* xb = x + (size_t)b * 262144 + n0 + nn;
#pragma unroll
        for (int cc = 0; cc < 16; ++cc) {
            int c = cc * 4 + r;
            X[c * 65 + nn] = xb[(size_t)c * 4096];
        }
    }
    __syncthreads();

    {   // xT: 32 n rows, 8 threads per 128B row
        const int n8 = tid >> 3, c8 = tid & 7;
        const int n = (half << 5) + n8;
        unsigned u[4];
#pragma unroll
        for (int j = 0; j < 4; ++j) {
            unsigned lo = f2bf(X[(c8 * 8 + 2 * j) * 65 + n] * QS);
            unsigned hi = f2bf(X[(c8 * 8 + 2 * j + 1) * 65 + n] * QS);
            u[j] = lo | (hi << 16);
        }
        uint4 pk; pk.x = u[0]; pk.y = u[1]; pk.z = u[2]; pk.w = u[3];
        *(uint4*)(xT + (((size_t)((b << 12) + n0 + n)) << 6) + (c8 << 3)) = pk;
    }

    {   // V = relu(bn1(conv1x1)): 32 output channels for this half
        const int n = tid & 63, og = tid >> 6;
        float rX[64];
#pragma unroll
        for (int c = 0; c < 64; ++c) rX[c] = X[c * 65 + n];
        unsigned short* vb = vbf + (((size_t)(b << 6)) << 12) + n0 + n;
#pragma unroll 2
        for (int oo = 0; oo < 8; ++oo) {
            int o = (half << 5) + og * 8 + oo;
            float inv = g1[o] * rsqrtf(v1[o] + 1e-5f);
            float sh  = b1[o] - m1[o] * inv;
            float acc = 0.f;
#pragma unroll
            for (int c = 0; c < 64; ++c) acc = fmaf(w1[o * 64 + c], rX[c], acc);
            vb[(size_t)o << 12] = (unsigned short)f2bf(fmaxf(fmaf(acc, inv, sh), 0.f));
        }
    }
}

// ---------------------------------------------------------------------------
// k_attn v13: balanced 8-wave design (no producer/consumer split).
// Wave w -> O-quadrant (s=w&1, t=(w>>1)&1) and tile-parity par=w>>2.
// Per phase p (tiles 2p, 2p+1): each wave computes QK quadrant (s,t) of
// tile 2p+par (A/K and B/V fragments loaded DIRECTLY from global, L2-hot,
// register-prefetched one phase ahead -> no Klds/Vlds), exp2+pack -> P to
// Plds[p&1][par], ONE barrier, then PV for its tile into a private O
// partial. P is 4-buffered so a single barrier per phase is sufficient
// (34 barriers vs 66 in v12). Epilogue combines par0/par1 O partials and
// the 8 per-wave denominator partials via LDS. Layouts (swizzle, pack,
// fragment maps, stores) byte-identical to v12's verified ones.
// grid 512 = (b=XCD, qgrp), 2 blocks/CU.
// ---------------------------------------------------------------------------
__global__ __launch_bounds__(512, 4) void k_attn(
    const unsigned short* __restrict__ xT, const unsigned short* __restrict__ vbf,
    unsigned short* __restrict__ outO)
{
    __shared__ __align__(16) unsigned short Plds[2][2][64 * 64]; // [p&1][par][n][m] swz8
    __shared__ float rsLds[8][32];
    __shared__ float denomT[64];

    const int b    = blockIdx.x & 7;          // batch == XCD slice
    const int qgrp = blockIdx.x >> 3;         // 0..63
    const int tid  = threadIdx.x;
    const int w = tid >> 6, lane = tid & 63;
    const int l31 = lane & 31, half = lane >> 5;
    const int qbase = qgrp << 6;
    const int qd = w & 3, par = w >> 2;
    const int s = qd & 1;      // m-half (QK) / d-half (PV)
    const int t = qd >> 1;     // n-half
    const int nrow = (t << 5) + l31;

    // ---- Q fragments (B operand), rows n = qbase + t*32 + l31 ----
    s16x8 Bq[4];
    {
        const unsigned short* qr = xT +
            (((size_t)((b << 12) + qbase + (t << 5) + l31)) << 6) + (half << 3);
#pragma unroll
        for (int kk = 0; kk < 4; ++kk) {
            CvtI4 c; c.i = *(const int4*)(qr + (kk << 4));
            Bq[kk] = c.s;
        }
    }

    // ---- direct-global fragment bases ----
    // A (K rows):  xT[b][tau*64 + s*32 + l31][kk*16 + half*8 ..]
    const unsigned short* aBase = xT +
        (((size_t)((b << 12) + (s << 5) + l31)) << 6) + (half << 3);
    // B (V rows):  vbf[b][s*32 + l31][tau*64 + ks*16 + half*8 ..]
    const unsigned short* vBase = vbf +
        (((size_t)((b << 6) + (s << 5) + l31)) << 12) + (half << 3);

    int4 apre[4], vpre[4];
    {
        const int tau = par;                       // phase-0 tile for this wave
        const unsigned short* ap = aBase + ((size_t)tau << 12);
        const unsigned short* vp = vBase + (tau << 6);
#pragma unroll
        for (int kk = 0; kk < 4; ++kk) apre[kk] = *(const int4*)(ap + (kk << 4));
#pragma unroll
        for (int ks = 0; ks < 4; ++ks) vpre[ks] = *(const int4*)(vp + (ks << 4));
    }

    f32x16 O = {0.f,0.f,0.f,0.f,0.f,0.f,0.f,0.f,0.f,0.f,0.f,0.f,0.f,0.f,0.f,0.f};
    float rs = 0.f;

    for (int p = 0; p < 32; ++p) {
        unsigned short* Pb = Plds[p & 1][par];

        // ---- QK quadrant (s,t) of tile 2p+par ----
        f32x16 S = {0.f,0.f,0.f,0.f,0.f,0.f,0.f,0.f,0.f,0.f,0.f,0.f,0.f,0.f,0.f,0.f};
        {
            s16x8 Ak[4];
#pragma unroll
            for (int kk = 0; kk < 4; ++kk) { CvtI4 c; c.i = apre[kk]; Ak[kk] = c.s; }
            __builtin_amdgcn_s_setprio(1);
            S = __builtin_amdgcn_mfma_f32_32x32x16_bf16(Ak[0], Bq[0], S, 0, 0, 0);
            S = __builtin_amdgcn_mfma_f32_32x32x16_bf16(Ak[1], Bq[1], S, 0, 0, 0);
            S = __builtin_amdgcn_mfma_f32_32x32x16_bf16(Ak[2], Bq[2], S, 0, 0, 0);
            S = __builtin_amdgcn_mfma_f32_32x32x16_bf16(Ak[3], Bq[3], S, 0, 0, 0);
            __builtin_amdgcn_s_setprio(0);
        }
        {   // prefetch A fragments for next phase (clamped dup at tail)
            const int tn = (p < 31) ? (((p + 1) << 1) + par) : 63;
            const unsigned short* ap = aBase + ((size_t)tn << 12);
#pragma unroll
            for (int kk = 0; kk < 4; ++kk) apre[kk] = *(const int4*)(ap + (kk << 4));
        }
        // ---- softmax partial + bf16 pack + P write ----
#pragma unroll
        for (int q = 0; q < 4; ++q) {
            float p0 = __builtin_amdgcn_exp2f(S[4*q+0]);
            float p1 = __builtin_amdgcn_exp2f(S[4*q+1]);
            float p2 = __builtin_amdgcn_exp2f(S[4*q+2]);
            float p3 = __builtin_amdgcn_exp2f(S[4*q+3]);
            rs += (p0 + p1) + (p2 + p3);
            union { float f; unsigned u; } a0, a1, a2, a3;
            a0.f = p0; a1.f = p1; a2.f = p2; a3.f = p3;
            uint2 pk;
            pk.x = __builtin_amdgcn_perm(a1.u + 0x8000u, a0.u + 0x8000u, 0x07060302u);
            pk.y = __builtin_amdgcn_perm(a3.u + 0x8000u, a2.u + 0x8000u, 0x07060302u);
            int c8 = (s << 2) + q;
            *(uint2*)(Pb + (nrow << 6) + ((c8 ^ (nrow & 7)) << 3) + (half << 2)) = pk;
        }

        __syncthreads();   // P[p&1][*] complete; single barrier per phase

        // ---- PV quadrant (s,t) on tile 2p+par ----
        {
            __builtin_amdgcn_s_setprio(1);
#pragma unroll
            for (int ks = 0; ks < 4; ++ks) {
                int c = (ks << 1) + half;
                const s16x8 Ap = *(const s16x8*)(Pb + (nrow << 6) + ((c ^ (nrow & 7)) << 3));
                CvtI4 cv; cv.i = vpre[ks];
                O = __builtin_amdgcn_mfma_f32_32x32x16_bf16(Ap, cv.s, O, 0, 0, 0);
            }
            __builtin_amdgcn_s_setprio(0);
        }
        {   // prefetch V fragments for next phase (clamped dup at tail)
            const int tn = (p < 31) ? (((p + 1) << 1) + par) : 63;
            const unsigned short* vp = vBase + (tn << 6);
#pragma unroll
            for (int ks = 0; ks < 4; ++ks) vpre[ks] = *(const int4*)(vp + (ks << 4));
        }
    }

    // ================= epilogue =================
    rs += __shfl_xor(rs, 32);
    if (half == 0) rsLds[w][l31] = rs;
    __syncthreads();   // also guards Plds reuse as f32 O-exchange scratch

    if (tid < 64) {
        int tt = tid >> 5, n = tid & 31;
        denomT[tid] = (rsLds[2*tt][n] + rsLds[2*tt+1][n]) +
                      (rsLds[4+2*tt][n] + rsLds[5+2*tt][n]);
    }
    float* Ox = (float*)&Plds[0][0][0];   // 4 quadrants x 32x32 f32 = 16 KB
    if (par == 1) {
#pragma unroll
        for (int r = 0; r < 16; ++r) {
            int row = (r & 3) + ((r >> 2) << 3) + (half << 2);
            Ox[(qd << 10) + (row << 5) + l31] = O[r];
        }
    }
    __syncthreads();

    if (par == 0) {
        const int nb = (b << 12) + qbase;
#pragma unroll
        for (int r = 0; r < 16; ++r) {
            int row = (r & 3) + ((r >> 2) << 3) + (half << 2);
            float o = O[r] + Ox[(qd << 10) + (row << 5) + l31];
            int n = (t << 5) + row;
            float inv = 1.f / denomT[n];
            outO[((size_t)(nb + n) << 6) + (s << 5) + l31] = (unsigned short)f2bf(o * inv);
        }
    }
}

// ---------------------------------------------------------------------------
// k_post: stage 3-row attn window (bf16, already normalized) into LDS ->
// dwconv3x3 + BN2 + ReLU -> LDS -> pointwise(w3) + BN3 + residual.
// grid 512 = (b, h), 256 thr.
// ---------------------------------------------------------------------------
__global__ __launch_bounds__(256) void k_post(
    const unsigned short* __restrict__ Obase,
    const float* __restrict__ x,
    const float* __restrict__ w2,
    const float* __restrict__ g2, const float* __restrict__ b2,
    const float* __restrict__ m2, const float* __restrict__ v2,
    const float* __restrict__ w3,
    const float* __restrict__ g3, const float* __restrict__ b3,
    const float* __restrict__ m3, const float* __restrict__ v3,
    float* __restrict__ out)
{
    __shared__ float W[3][64 * 66];
    __shared__ float T2[64 * 66];

    const int b = blockIdx.x >> 6;
    const int h = blockIdx.x & 63;
    const int tid = threadIdx.x;

#pragma unroll
    for (int r = 0; r < 3; ++r) {
        int hh = h + r - 1;
        if (hh >= 0 && hh <= 63) {
#pragma unroll
            for (int i = 0; i < 2; ++i) {
                int lin = (i << 8) + tid;            // 512 = 64 w x 8 chunks
                int w = lin >> 3, cg = lin & 7;
                size_t npos = (size_t)((b << 12) + (hh << 6) + w);
                uint4 v = *(const uint4*)(Obase + (npos << 6) + (cg << 3));
                float* Wd = &W[r][w * 66 + (cg << 3)];
                union { float f; unsigned u; } t;
                t.u = v.x << 16;         Wd[0] = t.f;
                t.u = v.x & 0xFFFF0000u; Wd[1] = t.f;
                t.u = v.y << 16;         Wd[2] = t.f;
                t.u = v.y & 0xFFFF0000u; Wd[3] = t.f;
                t.u = v.z << 16;         Wd[4] = t.f;
                t.u = v.z & 0xFFFF0000u; Wd[5] = t.f;
                t.u = v.w << 16;         Wd[6] = t.f;
                t.u = v.w & 0xFFFF0000u; Wd[7] = t.f;
            }
        } else {
#pragma unroll
            for (int i = 0; i < 2; ++i) {
                int lin = (i << 8) + tid;
                float* Wd = &W[r][(lin >> 3) * 66 + ((lin & 7) << 3)];
#pragma unroll
                for (int j = 0; j < 8; ++j) Wd[j] = 0.f;
            }
        }
    }
    __syncthreads();

    const int w = tid & 63, cq = tid >> 6;
    float t16[16];
#pragma unroll
    for (int i = 0; i < 16; ++i) t16[i] = 0.f;

#pragma unroll
    for (int ky = 0; ky < 3; ++ky) {
#pragma unroll
        for (int kx = 0; kx < 3; ++kx) {
            int ww = w + kx - 1;
            if (ww < 0 || ww > 63) continue;
            const int k = ky * 3 + kx;
            const float* Wr = &W[ky][ww * 66 + (cq << 4)];
#pragma unroll
            for (int i = 0; i < 4; ++i) {
                float4 a = *(const float4*)(Wr + (i << 2));
                int c = (cq << 4) + (i << 2);
                t16[i * 4 + 0] = fmaf(w2[(c + 0) * 9 + k], a.x, t16[i * 4 + 0]);
                t16[i * 4 + 1] = fmaf(w2[(c + 1) * 9 + k], a.y, t16[i * 4 + 1]);
                t16[i * 4 + 2] = fmaf(w2[(c + 2) * 9 + k], a.z, t16[i * 4 + 2]);
                t16[i * 4 + 3] = fmaf(w2[(c + 3) * 9 + k], a.w, t16[i * 4 + 3]);
            }
        }
    }
#pragma unroll
    for (int i = 0; i < 16; ++i) {
        int c = (cq << 4) + i;
        float inv = g2[c] * rsqrtf(v2[c] + 1e-5f);
        float sh  = b2[c] - m2[c] * inv;
        T2[w * 66 + c] = fmaxf(fmaf(t16[i], inv, sh), 0.f);
    }
    __syncthreads();

    float rT[64];
#pragma unroll
    for (int c4 = 0; c4 < 16; ++c4)
        *(float4*)&rT[c4 << 2] = *(const float4*)&T2[w * 66 + (c4 << 2)];

    const int hw = (h << 6) + w;
#pragma unroll 2
    for (int oo = 0; oo < 16; ++oo) {
        int o = (cq << 4) + oo;
        float inv = g3[o] * rsqrtf(v3[o] + 1e-5f);
        float sh  = b3[o] - m3[o] * inv;
        float acc = 0.f;
#pragma unroll
        for (int c = 0; c < 64; ++c) acc = fmaf(w3[o * 64 + c], rT[c], acc);
        size_t idx = (((size_t)((b << 6) + o)) << 12) + hw;
        out[idx] = fmaf(acc, inv, sh) + x[idx];
    }
}

// ---------------------------------------------------------------------------
extern "C" void kernel_launch(void* const* d_in, const int* in_sizes, int n_in,
                              void* d_out, int out_size, void* d_ws, size_t ws_size,
                              hipStream_t stream)
{
    const float* x  = (const float*)d_in[0];
    const float* w1 = (const float*)d_in[1];
    const float* g1 = (const float*)d_in[2];
    const float* b1 = (const float*)d_in[3];
    const float* m1 = (const float*)d_in[4];
    const float* v1 = (const float*)d_in[5];
    const float* w2 = (const float*)d_in[6];
    const float* g2 = (const float*)d_in[7];
    const float* b2 = (const float*)d_in[8];
    const float* m2 = (const float*)d_in[9];
    const float* v2 = (const float*)d_in[10];
    const float* w3 = (const float*)d_in[11];
    const float* g3 = (const float*)d_in[12];
    const float* b3 = (const float*)d_in[13];
    const float* m3 = (const float*)d_in[14];
    const float* v3 = (const float*)d_in[15];
    float* out = (float*)d_out;

    // ws: xT 4MB | vbf 4MB | O 4MB (bf16, normalized)
    unsigned short* xT  = (unsigned short*)d_ws;
    unsigned short* vbf = xT + (size_t)8 * 4096 * 64;
    unsigned short* Obase = (unsigned short*)((char*)d_ws + (8u << 20));

    k_prep<<<1024, 256, 0, stream>>>(x, w1, g1, b1, m1, v1, xT, vbf);
    k_attn<<<512, 512, 0, stream>>>(xT, vbf, Obase);
    k_post<<<512, 256, 0, stream>>>(Obase, x, w2, g2, b2, m2, v2,
                                    w3, g3, b3, m3, v3, out);
}

// Round 3
// 185.540 us; speedup vs baseline: 1.3861x; 1.3861x over previous
//
#include <hip/hip_runtime.h>
#include <stdint.h>

typedef __attribute__((ext_vector_type(8)))  short s16x8;   // 8 x bf16
typedef __attribute__((ext_vector_type(16))) float f32x16;  // 32x32 MFMA acc
typedef __attribute__((ext_vector_type(2)))  unsigned u32x2;

union CvtI4 { int4 i; s16x8 s; };
union CvtU4 { uint4 u; s16x8 s; };

__device__ __forceinline__ unsigned f2bf(float f) {
    union { float f; unsigned u; } v; v.f = f;
    return (v.u + 0x7fffu + ((v.u >> 16) & 1u)) >> 16;     // RNE
}

// pack two f32 -> (bf16(lo) | bf16(hi)<<16), round-half-up (v12-verified idiom)
__device__ __forceinline__ unsigned packbf(float lo, float hi) {
    union { float f; unsigned u; } a0, a1;
    a0.f = lo; a1.f = hi;
    return __builtin_amdgcn_perm(a1.u + 0x8000u, a0.u + 0x8000u, 0x07060302u);
}

// ---------------------------------------------------------------------------
// k_prep: grid 1024 = (b, n0-chunk, half). LDS-transpose x tile ->
//   xT[b][n][c] = bf16(x * sqrt(log2e/8)), vbf[b][c][n] = bf16(relu(bn1(w1.x)))
// ---------------------------------------------------------------------------
__global__ __launch_bounds__(256) void k_prep(
    const float* __restrict__ x, const float* __restrict__ w1,
    const float* __restrict__ g1, const float* __restrict__ b1,
    const float* __restrict__ m1, const float* __restrict__ v1,
    unsigned short* __restrict__ xT, unsigned short* __restrict__ vbf)
{
    __shared__ float X[64 * 65];   // [c][n] pad+1
    const int b    = blockIdx.x >> 7;
    const int n0   = ((blockIdx.x >> 1) & 63) << 6;
    const int half = blockIdx.x & 1;
    const int tid  = threadIdx.x;
    const float QS = 0.42466090014400953f;   // sqrt(log2(e)/8)

    {
        const int r = tid >> 6, nn = tid & 63;
        const float* xb = x + (size_t)b * 262144 + n0 + nn;
#pragma unroll
        for (int cc = 0; cc < 16; ++cc) {
            int c = cc * 4 + r;
            X[c * 65 + nn] = xb[(size_t)c * 4096];
        }
    }
    __syncthreads();

    {   // xT: 32 n rows, 8 threads per 128B row
        const int n8 = tid >> 3, c8 = tid & 7;
        const int n = (half << 5) + n8;
        unsigned u[4];
#pragma unroll
        for (int j = 0; j < 4; ++j) {
            unsigned lo = f2bf(X[(c8 * 8 + 2 * j) * 65 + n] * QS);
            unsigned hi = f2bf(X[(c8 * 8 + 2 * j + 1) * 65 + n] * QS);
            u[j] = lo | (hi << 16);
        }
        uint4 pk; pk.x = u[0]; pk.y = u[1]; pk.z = u[2]; pk.w = u[3];
        *(uint4*)(xT + (((size_t)((b << 12) + n0 + n)) << 6) + (c8 << 3)) = pk;
    }

    {   // V = relu(bn1(conv1x1)): 32 output channels for this half
        const int n = tid & 63, og = tid >> 6;
        float rX[64];
#pragma unroll
        for (int c = 0; c < 64; ++c) rX[c] = X[c * 65 + n];
        unsigned short* vb = vbf + (((size_t)(b << 6)) << 12) + n0 + n;
#pragma unroll 2
        for (int oo = 0; oo < 8; ++oo) {
            int o = (half << 5) + og * 8 + oo;
            float inv = g1[o] * rsqrtf(v1[o] + 1e-5f);
            float sh  = b1[o] - m1[o] * inv;
            float acc = 0.f;
#pragma unroll
            for (int c = 0; c < 64; ++c) acc = fmaf(w1[o * 64 + c], rX[c], acc);
            vb[(size_t)o << 12] = (unsigned short)f2bf(fmaxf(fmaf(acc, inv, sh), 0.f));
        }
    }
}

// ---------------------------------------------------------------------------
// k_attn v15: 8 balanced waves, in-register P (no P LDS, no QK->PV barrier).
// Wave w = (qd = w&3, par = w>>2); qd -> (s = m-strip, t = n-half).
// Phase p handles tiles {2p, 2p+1}; wave works on tile 2p+par.
// QK: A = K rows (LDS, v12 swizzle), B = Q rows (regs). D col = n = lane&31,
// reg r -> m-offset (r&3)+8*(r>>2)+4*half  => P is lane-local in n.
// exp2 -> packbf pairs G[q] -> __builtin_amdgcn_permlane32_swap builds the
// PV A-fragment: swap(a,b) -> (a.lo||b.lo, a.hi||b.hi), so
//   (dw0,dw2) = swap(G[2ksl].x, G[2ksl+1].x), (dw1,dw3) = swap(.y,.y).
// Each wave's PV covers only its own s-strip of m (k-slices 2s..2s+1);
// the missing half + tile-parity are tree-summed over waves in the epilogue.
// K/V double-buffered 2-tile phases, cooperative coalesced staging (512 thr),
// register prefetch 1 phase ahead. ONE barrier per phase (33 total).
// LDS exactly 64KB -> 2 blocks/CU. grid 512 = (b=XCD, qgrp).
// ---------------------------------------------------------------------------
__global__ __launch_bounds__(512, 4) void k_attn(
    const unsigned short* __restrict__ xT, const unsigned short* __restrict__ vbf,
    unsigned short* __restrict__ outO)
{
    __shared__ __align__(16) unsigned short Kl[2][2][64 * 64];  // [buf][pt][m][c] swz8
    __shared__ __align__(16) unsigned short Vl[2][2][64 * 64];  // [buf][pt][d][m] swz8

    const int b    = blockIdx.x & 7;          // batch == XCD slice
    const int qgrp = blockIdx.x >> 3;         // 0..63
    const int tid  = threadIdx.x;
    const int w = tid >> 6, lane = tid & 63;
    const int l31 = lane & 31, half = lane >> 5;
    const int qbase = qgrp << 6;
    const int qd = w & 3, par = w >> 2;
    const int s = qd & 1;      // m-strip (QK) / PV k-slice group
    const int t = qd >> 1;     // n-half

    // ---- Q fragments (B operand), rows n = qbase + t*32 + l31 ----
    s16x8 Bq[4];
    {
        const unsigned short* qr = xT +
            (((size_t)((b << 12) + qbase + (t << 5) + l31)) << 6) + (half << 3);
#pragma unroll
        for (int kk = 0; kk < 4; ++kk) {
            CvtI4 c; c.i = *(const int4*)(qr + (kk << 4));
            Bq[kk] = c.s;
        }
    }

    // ---- cooperative staging mapping (512 threads, 2 tiles/phase) ----
    const int pt = tid >> 8;            // tile parity this thread stages
    const int sr = (tid >> 3) & 31;     // rows sr and sr+32
    const int sc = tid & 7;             // 16B chunk
    const unsigned short* kBase = xT  + ((size_t)b << 18) + (sr << 6) + (sc << 3);
    const unsigned short* vBase = vbf + ((size_t)b << 18) + ((size_t)sr << 12) + (sc << 3);
    const int kx  = (sc ^ (sr & 7)) << 3;          // (sr+32)&7 == sr&7
    const int d0  = (sr << 6) + kx;
    const int d1  = ((sr + 32) << 6) + kx;

    int4 kpA, kpB, vpA, vpB;

    // ================= prologue: stage T0 direct, prefetch T1 =================
    {
        int4 a0 = *(const int4*)(kBase + ((size_t)pt << 12));
        int4 a1 = *(const int4*)(kBase + ((size_t)pt << 12) + (32 << 6));
        int4 b0 = *(const int4*)(vBase + (pt << 6));
        int4 b1v = *(const int4*)(vBase + ((size_t)32 << 12) + (pt << 6));
        unsigned short* Kd = &Kl[0][pt][0];
        unsigned short* Vd = &Vl[0][pt][0];
        *(int4*)(Kd + d0) = a0; *(int4*)(Kd + d1) = a1;
        *(int4*)(Vd + d0) = b0; *(int4*)(Vd + d1) = b1v;
        const int t1 = 2 + pt;
        kpA = *(const int4*)(kBase + ((size_t)t1 << 12));
        kpB = *(const int4*)(kBase + ((size_t)t1 << 12) + (32 << 6));
        vpA = *(const int4*)(vBase + (t1 << 6));
        vpB = *(const int4*)(vBase + ((size_t)32 << 12) + (t1 << 6));
    }
    __syncthreads();

    f32x16 O[2];
#pragma unroll
    for (int dl = 0; dl < 2; ++dl)
#pragma unroll
        for (int r = 0; r < 16; ++r) O[dl][r] = 0.f;
    float rs = 0.f;

    const int km = (s << 5) + l31;

    // ================= main loop: 32 phases, 1 barrier each =================
    for (int p = 0; p < 32; ++p) {
        // stage T(p+1) from regs into buf[(p+1)&1]
        {
            unsigned short* Kd = &Kl[(p + 1) & 1][pt][0];
            unsigned short* Vd = &Vl[(p + 1) & 1][pt][0];
            *(int4*)(Kd + d0) = kpA; *(int4*)(Kd + d1) = kpB;
            *(int4*)(Vd + d0) = vpA; *(int4*)(Vd + d1) = vpB;
        }
        // prefetch T(p+2) (clamped dup at tail, never read)
        {
            int tn = ((p + 2) << 1) + pt; if (tn > 63) tn = 63;
            kpA = *(const int4*)(kBase + ((size_t)tn << 12));
            kpB = *(const int4*)(kBase + ((size_t)tn << 12) + (32 << 6));
            vpA = *(const int4*)(vBase + (tn << 6));
            vpB = *(const int4*)(vBase + ((size_t)32 << 12) + (tn << 6));
        }

        // ---- QK quadrant (s,t) of tile 2p+par ----
        const unsigned short* Kb = &Kl[p & 1][par][0];
        s16x8 Ak[4];
#pragma unroll
        for (int kk = 0; kk < 4; ++kk)
            Ak[kk] = *(const s16x8*)(Kb + (km << 6) + ((((kk << 1) + half) ^ (km & 7)) << 3));
        f32x16 S = {0.f,0.f,0.f,0.f,0.f,0.f,0.f,0.f,0.f,0.f,0.f,0.f,0.f,0.f,0.f,0.f};
        __builtin_amdgcn_s_setprio(1);
        S = __builtin_amdgcn_mfma_f32_32x32x16_bf16(Ak[0], Bq[0], S, 0, 0, 0);
        S = __builtin_amdgcn_mfma_f32_32x32x16_bf16(Ak[1], Bq[1], S, 0, 0, 0);
        S = __builtin_amdgcn_mfma_f32_32x32x16_bf16(Ak[2], Bq[2], S, 0, 0, 0);
        S = __builtin_amdgcn_mfma_f32_32x32x16_bf16(Ak[3], Bq[3], S, 0, 0, 0);
        __builtin_amdgcn_s_setprio(0);

        // ---- exp2 + pack to bf16 pairs (m-group q, lane-local in n) ----
        uint2 G[4];
#pragma unroll
        for (int q = 0; q < 4; ++q) {
            float p0 = __builtin_amdgcn_exp2f(S[4*q+0]);
            float p1 = __builtin_amdgcn_exp2f(S[4*q+1]);
            float p2 = __builtin_amdgcn_exp2f(S[4*q+2]);
            float p3 = __builtin_amdgcn_exp2f(S[4*q+3]);
            rs += (p0 + p1) + (p2 + p3);
            G[q].x = packbf(p0, p1);
            G[q].y = packbf(p2, p3);
        }

        // ---- PV: in-register P via permlane32_swap; B = V rows from LDS ----
        const unsigned short* Vb = &Vl[p & 1][par][0];
        __builtin_amdgcn_s_setprio(1);
#pragma unroll
        for (int ksl = 0; ksl < 2; ++ksl) {
            // swap(a,b) -> r.x = a.lo||b.lo (dw-low), r.y = a.hi||b.hi (dw-high)
            u32x2 r0 = __builtin_amdgcn_permlane32_swap(G[2*ksl].x, G[2*ksl+1].x, false, false);
            u32x2 r1 = __builtin_amdgcn_permlane32_swap(G[2*ksl].y, G[2*ksl+1].y, false, false);
            CvtU4 ac;
            ac.u.x = r0.x;   // elems 0,1  (src half 0)
            ac.u.y = r1.x;   // elems 2,3  (src half 0)
            ac.u.z = r0.y;   // elems 4,5  (src half 1)
            ac.u.w = r1.y;   // elems 6,7  (src half 1)
            const s16x8 Ap = ac.s;
#pragma unroll
            for (int dl = 0; dl < 2; ++dl) {
                const int drow = (dl << 5) + l31;
                const int cch = (s << 2) + (ksl << 1) + half;   // global 16B chunk in m
                const s16x8 Bv = *(const s16x8*)(Vb + (drow << 6) + ((cch ^ (drow & 7)) << 3));
                O[dl] = __builtin_amdgcn_mfma_f32_32x32x16_bf16(Ap, Bv, O[dl], 0, 0, 0);
            }
        }
        __builtin_amdgcn_s_setprio(0);

        __syncthreads();
    }

    // ================= epilogue: tree-sum O over (s,par); denom; store =====
    float* scr  = (float*)&Kl[0][0][0];        // 8192 f32 (par-merge scratch)
    float* scr2 = (float*)&Vl[0][0][0];        // 4096 f32 (s-merge scratch)
    float* rsL  = scr2 + 4096;                 // 256 f32: [w][l31]
    float* dnm  = rsL + 256;                   // 64 f32

    rs += __shfl_xor(rs, 32);
    if (half == 0) rsL[(w << 5) + l31] = rs;
    if (par == 1) {
#pragma unroll
        for (int dl = 0; dl < 2; ++dl)
#pragma unroll
            for (int r = 0; r < 16; ++r)
                scr[((((qd << 1) + dl)) << 10) + (r << 6) + lane] = O[dl][r];
    }
    __syncthreads();

    if (tid < 64) {
        int tt = tid >> 5, n = tid & 31;
        dnm[tid] = (rsL[((tt << 1) << 5) + n] + rsL[(((tt << 1) + 1) << 5) + n]) +
                   (rsL[(((tt << 1) + 4) << 5) + n] + rsL[(((tt << 1) + 5) << 5) + n]);
    }
    if (par == 0) {
#pragma unroll
        for (int dl = 0; dl < 2; ++dl)
#pragma unroll
            for (int r = 0; r < 16; ++r)
                O[dl][r] += scr[((((qd << 1) + dl)) << 10) + (r << 6) + lane];
        if (s == 1) {
#pragma unroll
            for (int dl = 0; dl < 2; ++dl)
#pragma unroll
                for (int r = 0; r < 16; ++r)
                    scr2[((((t << 1) + dl)) << 10) + (r << 6) + lane] = O[dl][r];
        }
    }
    __syncthreads();

    if (par == 0 && s == 0) {
        const int nb = (b << 12) + qbase;
#pragma unroll
        for (int r = 0; r < 16; ++r) {
            int rowoff = (r & 3) + ((r >> 2) << 3) + (half << 2);
            int n = (t << 5) + rowoff;
            float inv = 1.f / dnm[n];
#pragma unroll
            for (int dl = 0; dl < 2; ++dl) {
                float o = O[dl][r] + scr2[((((t << 1) + dl)) << 10) + (r << 6) + lane];
                outO[((size_t)(nb + n) << 6) + (dl << 5) + l31] =
                    (unsigned short)f2bf(o * inv);
            }
        }
    }
}

// ---------------------------------------------------------------------------
// k_post: stage 3-row attn window (bf16, already normalized) into LDS ->
// dwconv3x3 + BN2 + ReLU -> LDS -> pointwise(w3) + BN3 + residual.
// grid 512 = (b, h), 256 thr.
// ---------------------------------------------------------------------------
__global__ __launch_bounds__(256) void k_post(
    const unsigned short* __restrict__ Obase,
    const float* __restrict__ x,
    const float* __restrict__ w2,
    const float* __restrict__ g2, const float* __restrict__ b2,
    const float* __restrict__ m2, const float* __restrict__ v2,
    const float* __restrict__ w3,
    const float* __restrict__ g3, const float* __restrict__ b3,
    const float* __restrict__ m3, const float* __restrict__ v3,
    float* __restrict__ out)
{
    __shared__ float W[3][64 * 66];
    __shared__ float T2[64 * 66];

    const int b = blockIdx.x >> 6;
    const int h = blockIdx.x & 63;
    const int tid = threadIdx.x;

#pragma unroll
    for (int r = 0; r < 3; ++r) {
        int hh = h + r - 1;
        if (hh >= 0 && hh <= 63) {
#pragma unroll
            for (int i = 0; i < 2; ++i) {
                int lin = (i << 8) + tid;            // 512 = 64 w x 8 chunks
                int w = lin >> 3, cg = lin & 7;
                size_t npos = (size_t)((b << 12) + (hh << 6) + w);
                uint4 v = *(const uint4*)(Obase + (npos << 6) + (cg << 3));
                float* Wd = &W[r][w * 66 + (cg << 3)];
                union { float f; unsigned u; } t;
                t.u = v.x << 16;         Wd[0] = t.f;
                t.u = v.x & 0xFFFF0000u; Wd[1] = t.f;
                t.u = v.y << 16;         Wd[2] = t.f;
                t.u = v.y & 0xFFFF0000u; Wd[3] = t.f;
                t.u = v.z << 16;         Wd[4] = t.f;
                t.u = v.z & 0xFFFF0000u; Wd[5] = t.f;
                t.u = v.w << 16;         Wd[6] = t.f;
                t.u = v.w & 0xFFFF0000u; Wd[7] = t.f;
            }
        } else {
#pragma unroll
            for (int i = 0; i < 2; ++i) {
                int lin = (i << 8) + tid;
                float* Wd = &W[r][(lin >> 3) * 66 + ((lin & 7) << 3)];
#pragma unroll
                for (int j = 0; j < 8; ++j) Wd[j] = 0.f;
            }
        }
    }
    __syncthreads();

    const int w = tid & 63, cq = tid >> 6;
    float t16[16];
#pragma unroll
    for (int i = 0; i < 16; ++i) t16[i] = 0.f;

#pragma unroll
    for (int ky = 0; ky < 3; ++ky) {
#pragma unroll
        for (int kx = 0; kx < 3; ++kx) {
            int ww = w + kx - 1;
            if (ww < 0 || ww > 63) continue;
            const int k = ky * 3 + kx;
            const float* Wr = &W[ky][ww * 66 + (cq << 4)];
#pragma unroll
            for (int i = 0; i < 4; ++i) {
                float4 a = *(const float4*)(Wr + (i << 2));
                int c = (cq << 4) + (i << 2);
                t16[i * 4 + 0] = fmaf(w2[(c + 0) * 9 + k], a.x, t16[i * 4 + 0]);
                t16[i * 4 + 1] = fmaf(w2[(c + 1) * 9 + k], a.y, t16[i * 4 + 1]);
                t16[i * 4 + 2] = fmaf(w2[(c + 2) * 9 + k], a.z, t16[i * 4 + 2]);
                t16[i * 4 + 3] = fmaf(w2[(c + 3) * 9 + k], a.w, t16[i * 4 + 3]);
            }
        }
    }
#pragma unroll
    for (int i = 0; i < 16; ++i) {
        int c = (cq << 4) + i;
        float inv = g2[c] * rsqrtf(v2[c] + 1e-5f);
        float sh  = b2[c] - m2[c] * inv;
        T2[w * 66 + c] = fmaxf(fmaf(t16[i], inv, sh), 0.f);
    }
    __syncthreads();

    float rT[64];
#pragma unroll
    for (int c4 = 0; c4 < 16; ++c4)
        *(float4*)&rT[c4 << 2] = *(const float4*)&T2[w * 66 + (c4 << 2)];

    const int hw = (h << 6) + w;
#pragma unroll 2
    for (int oo = 0; oo < 16; ++oo) {
        int o = (cq << 4) + oo;
        float inv = g3[o] * rsqrtf(v3[o] + 1e-5f);
        float sh  = b3[o] - m3[o] * inv;
        float acc = 0.f;
#pragma unroll
        for (int c = 0; c < 64; ++c) acc = fmaf(w3[o * 64 + c], rT[c], acc);
        size_t idx = (((size_t)((b << 6) + o)) << 12) + hw;
        out[idx] = fmaf(acc, inv, sh) + x[idx];
    }
}

// ---------------------------------------------------------------------------
extern "C" void kernel_launch(void* const* d_in, const int* in_sizes, int n_in,
                              void* d_out, int out_size, void* d_ws, size_t ws_size,
                              hipStream_t stream)
{
    const float* x  = (const float*)d_in[0];
    const float* w1 = (const float*)d_in[1];
    const float* g1 = (const float*)d_in[2];
    const float* b1 = (const float*)d_in[3];
    const float* m1 = (const float*)d_in[4];
    const float* v1 = (const float*)d_in[5];
    const float* w2 = (const float*)d_in[6];
    const float* g2 = (const float*)d_in[7];
    const float* b2 = (const float*)d_in[8];
    const float* m2 = (const float*)d_in[9];
    const float* v2 = (const float*)d_in[10];
    const float* w3 = (const float*)d_in[11];
    const float* g3 = (const float*)d_in[12];
    const float* b3 = (const float*)d_in[13];
    const float* m3 = (const float*)d_in[14];
    const float* v3 = (const float*)d_in[15];
    float* out = (float*)d_out;

    // ws: xT 4MB | vbf 4MB | O 4MB (bf16, normalized)
    unsigned short* xT  = (unsigned short*)d_ws;
    unsigned short* vbf = xT + (size_t)8 * 4096 * 64;
    unsigned short* Obase = (unsigned short*)((char*)d_ws + (8u << 20));

    k_prep<<<1024, 256, 0, stream>>>(x, w1, g1, b1, m1, v1, xT, vbf);
    k_attn<<<512, 512, 0, stream>>>(xT, vbf, Obase);
    k_post<<<512, 256, 0, stream>>>(Obase, x, w2, g2, b2, m2, v2,
                                    w3, g3, b3, m3, v3, out);
}